// Round 7
// baseline (319.088 us; speedup 1.0000x reference)
//
#include <hip/hip_runtime.h>
#include <stdint.h>

typedef __attribute__((ext_vector_type(8))) short short8;
typedef __attribute__((ext_vector_type(4))) float f32x4;
typedef __attribute__((ext_vector_type(2))) float f32x2;
typedef __attribute__((ext_vector_type(4))) int   i32x4;
typedef __attribute__((ext_vector_type(4))) unsigned int u32x4;
typedef __attribute__((ext_vector_type(2))) unsigned int u32x2;

#define T_STEPS 200
#define BATCH   128
#define UNITS   256
#define N3      768
#define EMB_D   100

#define NG 8        // row groups (blocks in gru kernel)
#define RR 16       // batch rows per group (fills M=16 exactly)
#define GWAVES 16   // waves per gru block

#define W8_BYTES  (48 * 4 * 64 * 16)         // 196608 == 256*768 i8 frags
#define WFX_ELEMS (48 * 4 * 64 * 8)          // 98304  == 128*768 bf16 (K padded 100->128)
#define MX2_SLICE (16 * 64 * 12)             // ushorts per (t,g) slice == 16x768

#define NLOG2E  -1.4426950408889634f         // -log2(e), folded into z/r columns
#define N2LOG2E -2.8853900817779268f         // -2*log2(e), folded into c columns

#if __has_builtin(__builtin_amdgcn_exp2f)
#define EXP2(x) __builtin_amdgcn_exp2f(x)
#else
#define EXP2(x) __expf((x) * 0.6931471805599453f)
#endif

__device__ __forceinline__ unsigned short f2bf(float f) {
  unsigned int u = __float_as_uint(f);
  u = (u + 0x7fffu + ((u >> 16) & 1u)) >> 16;   // RNE
  return (unsigned short)u;
}
__device__ __forceinline__ float sigmoidf_(float x) {
  return __builtin_amdgcn_rcpf(1.0f + __expf(-x));
}
__device__ __forceinline__ f32x2 exp2v(f32x2 a) {
  f32x2 r; r.x = EXP2(a.x); r.y = EXP2(a.y); return r;
}
__device__ __forceinline__ f32x2 min2(f32x2 a, float b) {
  f32x2 bb = {b, b};
  return __builtin_elementwise_min(a, bb);
}

// ---------------- kernel 0a: per-column absmax of rkernel -> cm[768] ----------------
__global__ void scale_kernel(const float* __restrict__ rkern, float* __restrict__ cm) {
  __shared__ float red[256];
  int t = threadIdx.x;
  int n = blockIdx.x * 32 + (t & 31);
  int k0 = (t >> 5) * 32;
  float m = 0.0f;
#pragma unroll 8
  for (int k = k0; k < k0 + 32; ++k) m = fmaxf(m, fabsf(rkern[k * N3 + n]));
  red[t] = m;
  __syncthreads();
  if (t < 32) {
    float mm = red[t];
#pragma unroll
    for (int s = 1; s < 8; ++s) mm = fmaxf(mm, red[t + 32 * s]);
    cm[blockIdx.x * 32 + t] = (mm > 0.0f) ? mm : 1.0f;
  }
}

// ------- kernel 0b: quantize rkernel->i8 frags; kernel->bf16 frags (log2e-folded) ----
__global__ void prep_kernel(const float* __restrict__ kern,
                            const float* __restrict__ rkern,
                            const float* __restrict__ bias_i,
                            const float* __restrict__ bias_r,
                            const float* __restrict__ cm,
                            signed char* __restrict__ w8,
                            unsigned short* __restrict__ wfx,
                            float* __restrict__ bsum) {
  int i = blockIdx.x * 256 + threadIdx.x;
  if (i < W8_BYTES) {
    // byte i = ((ntg*4 + kc)*64 + l)*16 + e  ->  rkernel[k][n] / cm[n] * 127
    int e = i & 15, l = (i >> 4) & 63, kc = (i >> 10) & 3, ntg = i >> 12;
    int r = (e & 3) + ((l >> 4) & 3) * 4 + ((e >> 2) & 3) * 16;  // k within 64-chunk
    int k = kc * 64 + r;
    int n = ntg * 16 + (l & 15);
    float v = rintf(rkern[k * N3 + n] * 127.0f / cm[n]);
    v = fminf(127.0f, fmaxf(-127.0f, v));
    w8[i] = (signed char)(int)v;
  } else if (i < W8_BYTES + WFX_ELEMS) {
    int j = i - W8_BYTES;
    int e = j & 7, l = (j >> 3) & 63, ks = (j >> 9) & 3, nt = j >> 11;
    int k = ks * 32 + (e >> 2) * 16 + ((l >> 4) & 3) * 4 + (e & 3);
    int n = nt * 16 + (l & 15);
    float gf = (n < 2 * UNITS) ? NLOG2E : N2LOG2E;   // fold exp2 scale into columns
    wfx[j] = (k < EMB_D) ? f2bf(kern[k * N3 + n] * gf) : (unsigned short)0;
  } else if (i < W8_BYTES + WFX_ELEMS + N3) {
    int c = i - (W8_BYTES + WFX_ELEMS);
    float gf = (c < 2 * UNITS) ? NLOG2E : N2LOG2E;
    bsum[c] = (bias_i[c] + ((c < 2 * UNITS) ? bias_r[c] : 0.0f)) * gf;
  }
}

// -------- kernel 1: MX2 = gru-lane-ordered bf16 (emb[inputs] @ kernel' + bsum') ------
// MX2 layout: [(t*8+g)][wv 0..15][lane 0..63][12]: per lane 12 ushorts =
// [z j=0..3][r j=0..3][c j=0..3] for (row=(lane>>4)*4+j, u=wv*16+(lane&15)).
__global__ __launch_bounds__(256) void mx_kernel(
    const int* __restrict__ inputs, const float* __restrict__ emb,
    const unsigned short* __restrict__ wfx, const float* __restrict__ bsum,
    unsigned short* __restrict__ MX2) {
  __shared__ unsigned short Af[4 * 64 * 8];   // 4 KB A-fragments (16 rows x K128)
  __shared__ unsigned short stg[MX2_SLICE];   // 24 KB scatter staging
  int tile = blockIdx.x;                      // tile == t*8 + g  (1600 tiles)
  int tid = threadIdx.x;
  int lane = tid & 63;
  int wv = tid >> 6;
  {
    short8 z = {0, 0, 0, 0, 0, 0, 0, 0};
    ((short8*)Af)[tid] = z;
  }
  __syncthreads();
  for (int e = tid; e < 16 * EMB_D; e += 256) {
    int r = e / EMB_D;
    int c = e - r * EMB_D;
    int m = tile * 16 + r;                    // m = t*128 + b
    int ti = m >> 7, b = m & 127;
    int word = inputs[b * T_STEPS + ti];
    float v = emb[word * EMB_D + c];
    int idx = ((c >> 5) * 64 + (r + 16 * ((c >> 2) & 3))) * 8 + ((c >> 4) & 1) * 4 + (c & 3);
    Af[idx] = f2bf(v);
  }
  __syncthreads();
  short8 a0 = ((short8*)Af)[0 * 64 + lane];
  short8 a1 = ((short8*)Af)[1 * 64 + lane];
  short8 a2 = ((short8*)Af)[2 * 64 + lane];
  short8 a3 = ((short8*)Af)[3 * 64 + lane];
  int laneg_base = (lane >> 4) * 16;          // ((row>>2)<<4), row = (lane>>4)*4 + j
  for (int q = 0; q < 12; ++q) {
    int nt = wv * 12 + q;
    f32x4 acc = {0.f, 0.f, 0.f, 0.f};
    const short8* bp = (const short8*)(wfx) + (nt * 4) * 64 + lane;
    acc = __builtin_amdgcn_mfma_f32_16x16x32_bf16(a0, bp[0],   acc, 0, 0, 0);
    acc = __builtin_amdgcn_mfma_f32_16x16x32_bf16(a1, bp[64],  acc, 0, 0, 0);
    acc = __builtin_amdgcn_mfma_f32_16x16x32_bf16(a2, bp[128], acc, 0, 0, 0);
    acc = __builtin_amdgcn_mfma_f32_16x16x32_bf16(a3, bp[192], acc, 0, 0, 0);
    int col = nt * 16 + (lane & 15);
    float bs = bsum[col];
    int gate = col >> 8, u = col & 255;
    int laneg = laneg_base | (u & 15);
    int base = ((u >> 4) * 64 + laneg) * 12 + gate * 4;
#pragma unroll
    for (int j = 0; j < 4; ++j) stg[base + j] = f2bf(acc[j] + bs);
  }
  __syncthreads();
  const u32x4* s = (const u32x4*)stg;
  u32x4* d = (u32x4*)(MX2 + (size_t)tile * MX2_SLICE);
  for (int i = tid; i < MX2_SLICE / 8; i += 256) d[i] = s[i];
}

// -------- kernel 2: block-local GRU, i8 MFMA, packed-f32 gates, wave-staggered -------
__global__ __launch_bounds__(1024) void gru_kernel(
    const unsigned short* __restrict__ MX2, const signed char* __restrict__ w8,
    const float* __restrict__ cm, const float* __restrict__ bias_r,
    const float* __restrict__ w_out, const float* __restrict__ b_out,
    float* __restrict__ out) {
  __shared__ i32x4 hAv[2][4 * 64];            // 8 KB: double-buffered h i8 A-frags
  __shared__ float hout[RR * UNITS];          // 16 KB: final h (fp32) for output GEMV

  int g = blockIdx.x;                          // 0..7
  int tid = threadIdx.x;
  int lane = tid & 63;
  int wv = tid >> 6;                           // 0..15

  // persistent weights: wave wv owns ntile triple {wv, 16+wv, 32+wv}
  i32x4 bz[4], br[4], bc[4];
  {
    const i32x4* wsrc = (const i32x4*)w8 + lane;
#pragma unroll
    for (int kc = 0; kc < 4; ++kc) {
      bz[kc] = wsrc[(size_t)((wv)*4 + kc) * 64];
      br[kc] = wsrc[(size_t)((16 + wv) * 4 + kc) * 64];
      bc[kc] = wsrc[(size_t)((32 + wv) * 4 + kc) * 64];
    }
  }
  if (tid < 256) { i32x4 z = {0, 0, 0, 0}; hAv[0][tid] = z; }

  int l15 = lane & 15;
  int u = wv * 16 + l15;
  const float inv = 1.0f / (127.0f * 127.0f);
  float szp = cm[u] * inv * NLOG2E;
  float srp = cm[u + UNITS] * inv * NLOG2E;
  float scp = cm[u + 2 * UNITS] * inv * N2LOG2E;
  float brcp = bias_r[2 * UNITS + u] * N2LOG2E;
  int r0 = (lane >> 4) * 4;                    // D-frag row base == gate rows r0..r0+3

  // hA byte-write base: row r0+j, unit u -> plane kc=(wv>>2) [1024 B each],
  // lane la=16*(l15>>2)+(r0+j), byte e=(l15&3)+4*(wv&3).  Buffer stride 4096 B.
  int hwb = (wv >> 2) * 1024 + (16 * (l15 >> 2) + r0) * 16 + (l15 & 3) + 4 * (wv & 3);

  f32x2 h01 = {0.0f, 0.0f}, h23 = {0.0f, 0.0f};
  const unsigned short* mxp = MX2 + ((size_t)g * GWAVES + wv) * 64 * 12 + (size_t)lane * 12;
  const size_t mxstride = (size_t)NG * GWAVES * 64 * 12;
  const float MAGIC = 12582912.0f;             // 2^23 + 2^22

  __syncthreads();

  for (int t = 0; t < T_STEPS; ++t) {
    u32x4 v4 = *(const u32x4*)(mxp);
    u32x2 v2 = *(const u32x2*)(mxp + 8);
    mxp += mxstride;

    const i32x4* hp = &hAv[t & 1][0];
    i32x4 af0 = hp[0 * 64 + lane];
    i32x4 af1 = hp[1 * 64 + lane];
    i32x4 af2 = hp[2 * 64 + lane];
    i32x4 af3 = hp[3 * 64 + lane];

    i32x4 az = {0, 0, 0, 0}, ar = {0, 0, 0, 0}, ac = {0, 0, 0, 0};
    f32x2 zg01, zg23, rg01, rg23;

#define CHAIN_Z do { \
    az = __builtin_amdgcn_mfma_i32_16x16x64_i8(af0, bz[0], az, 0, 0, 0); \
    az = __builtin_amdgcn_mfma_i32_16x16x64_i8(af1, bz[1], az, 0, 0, 0); \
    az = __builtin_amdgcn_mfma_i32_16x16x64_i8(af2, bz[2], az, 0, 0, 0); \
    az = __builtin_amdgcn_mfma_i32_16x16x64_i8(af3, bz[3], az, 0, 0, 0); } while (0)
#define CHAIN_R do { \
    ar = __builtin_amdgcn_mfma_i32_16x16x64_i8(af0, br[0], ar, 0, 0, 0); \
    ar = __builtin_amdgcn_mfma_i32_16x16x64_i8(af1, br[1], ar, 0, 0, 0); \
    ar = __builtin_amdgcn_mfma_i32_16x16x64_i8(af2, br[2], ar, 0, 0, 0); \
    ar = __builtin_amdgcn_mfma_i32_16x16x64_i8(af3, br[3], ar, 0, 0, 0); } while (0)
#define CHAIN_C do { \
    ac = __builtin_amdgcn_mfma_i32_16x16x64_i8(af0, bc[0], ac, 0, 0, 0); \
    ac = __builtin_amdgcn_mfma_i32_16x16x64_i8(af1, bc[1], ac, 0, 0, 0); \
    ac = __builtin_amdgcn_mfma_i32_16x16x64_i8(af2, bc[2], ac, 0, 0, 0); \
    ac = __builtin_amdgcn_mfma_i32_16x16x64_i8(af3, bc[3], ac, 0, 0, 0); } while (0)

    // ZR stage (packed f32; shared rcp across the j-pair AND across z/r):
    //   p_j = tz_j*tr_j; R = rcp(p0*p1); 1/p0 = p1*R; 1/p1 = p0*R.
#define ZR_VALU do { \
    f32x2 xz01 = {__uint_as_float(v4[0] << 16), __uint_as_float(v4[0] & 0xffff0000u)}; \
    f32x2 xz23 = {__uint_as_float(v4[1] << 16), __uint_as_float(v4[1] & 0xffff0000u)}; \
    f32x2 xr01 = {__uint_as_float(v4[2] << 16), __uint_as_float(v4[2] & 0xffff0000u)}; \
    f32x2 xr23 = {__uint_as_float(v4[3] << 16), __uint_as_float(v4[3] & 0xffff0000u)}; \
    f32x2 azf01 = {(float)az[0], (float)az[1]}, azf23 = {(float)az[2], (float)az[3]}; \
    f32x2 arf01 = {(float)ar[0], (float)ar[1]}, arf23 = {(float)ar[2], (float)ar[3]}; \
    f32x2 tz01 = exp2v(min2(azf01 * szp + xz01, 30.0f)) + 1.0f; \
    f32x2 tz23 = exp2v(min2(azf23 * szp + xz23, 30.0f)) + 1.0f; \
    f32x2 tr01 = exp2v(min2(arf01 * srp + xr01, 30.0f)) + 1.0f; \
    f32x2 tr23 = exp2v(min2(arf23 * srp + xr23, 30.0f)) + 1.0f; \
    f32x2 p01 = tz01 * tr01, p23 = tz23 * tr23; \
    float R01 = __builtin_amdgcn_rcpf(p01.x * p01.y); \
    float R23 = __builtin_amdgcn_rcpf(p23.x * p23.y); \
    f32x2 ip01 = {p01.y * R01, p01.x * R01}; \
    f32x2 ip23 = {p23.y * R23, p23.x * R23}; \
    zg01 = tr01 * ip01; rg01 = tz01 * ip01; \
    zg23 = tr23 * ip23; rg23 = tz23 * ip23; } while (0)

    // C stage + h update + quantized writeback (packed; shared rcp across j-pair)
#define C_VALU do { \
    f32x2 xc01 = {__uint_as_float(v2[0] << 16), __uint_as_float(v2[0] & 0xffff0000u)}; \
    f32x2 xc23 = {__uint_as_float(v2[1] << 16), __uint_as_float(v2[1] & 0xffff0000u)}; \
    f32x2 acf01 = {(float)ac[0], (float)ac[1]}, acf23 = {(float)ac[2], (float)ac[3]}; \
    f32x2 mc01 = acf01 * scp + brcp, mc23 = acf23 * scp + brcp; \
    f32x2 tc01 = exp2v(min2(rg01 * mc01 + xc01, 60.0f)) + 1.0f; \
    f32x2 tc23 = exp2v(min2(rg23 * mc23 + xc23, 60.0f)) + 1.0f; \
    float Rc01 = __builtin_amdgcn_rcpf(tc01.x * tc01.y); \
    float Rc23 = __builtin_amdgcn_rcpf(tc23.x * tc23.y); \
    f32x2 ic01 = {tc01.y * Rc01, tc01.x * Rc01}; \
    f32x2 ic23 = {tc23.y * Rc23, tc23.x * Rc23}; \
    f32x2 cand01 = ic01 * 2.0f - 1.0f, cand23 = ic23 * 2.0f - 1.0f; \
    h01 = zg01 * (h01 - cand01) + cand01; \
    h23 = zg23 * (h23 - cand23) + cand23; \
    f32x2 q01 = h01 * 127.0f + MAGIC, q23 = h23 * 127.0f + MAGIC; \
    hw[0]  = (signed char)(__float_as_uint(q01.x) & 0xFF); \
    hw[16] = (signed char)(__float_as_uint(q01.y) & 0xFF); \
    hw[32] = (signed char)(__float_as_uint(q23.x) & 0xFF); \
    hw[48] = (signed char)(__float_as_uint(q23.y) & 0xFF); } while (0)

    signed char* hw = (signed char*)hAv + (((t & 1) ^ 1) * 4096) + hwb;
    if (wv & 1) {
      // odd waves: all MFMAs first, VALU late (complements even waves' early VALU)
      CHAIN_Z; CHAIN_R; CHAIN_C;
      ZR_VALU; C_VALU;
    } else {
      CHAIN_Z; CHAIN_R;
      ZR_VALU;
      CHAIN_C;
      C_VALU;
    }
#undef CHAIN_Z
#undef CHAIN_R
#undef CHAIN_C
#undef ZR_VALU
#undef C_VALU
    __syncthreads();
  }

  // epilogue: logits = h @ w_out + b_out -> sigmoid
  hout[(r0 + 0) * UNITS + u] = h01.x;
  hout[(r0 + 1) * UNITS + u] = h01.y;
  hout[(r0 + 2) * UNITS + u] = h23.x;
  hout[(r0 + 3) * UNITS + u] = h23.y;
  __syncthreads();
  {
    float p = 0.0f;
#pragma unroll
    for (int k = 0; k < 4; ++k) p += hout[wv * UNITS + lane + 64 * k] * w_out[lane + 64 * k];
    p += __shfl_down(p, 32, 64);
    p += __shfl_down(p, 16, 64);
    p += __shfl_down(p, 8, 64);
    p += __shfl_down(p, 4, 64);
    p += __shfl_down(p, 2, 64);
    p += __shfl_down(p, 1, 64);
    if (lane == 0) out[g * RR + wv] = sigmoidf_(p + b_out[0]);
  }
}

extern "C" void kernel_launch(void* const* d_in, const int* in_sizes, int n_in,
                              void* d_out, int out_size, void* d_ws, size_t ws_size,
                              hipStream_t stream) {
  const int*   inputs = (const int*)d_in[0];
  const float* emb    = (const float*)d_in[1];
  const float* kern   = (const float*)d_in[2];
  const float* rkern  = (const float*)d_in[3];
  const float* bias_i = (const float*)d_in[4];
  const float* bias_r = (const float*)d_in[5];
  const float* w_out  = (const float*)d_in[6];
  const float* b_out  = (const float*)d_in[7];
  float* out = (float*)d_out;

  char* ws = (char*)d_ws;
  size_t off = 0;
  unsigned short* MX2 = (unsigned short*)(ws + off); off += (size_t)T_STEPS * 8 * MX2_SLICE * 2; // 39.3 MB
  signed char*    w8  = (signed char*)(ws + off);    off += (size_t)W8_BYTES;                    // 192 KB
  unsigned short* wfx = (unsigned short*)(ws + off); off += (size_t)WFX_ELEMS * 2;               // 192 KB
  float* cm   = (float*)(ws + off); off += (size_t)N3 * 4;
  float* bsum = (float*)(ws + off); off += (size_t)N3 * 4;
  if (off > ws_size) return;  // insufficient scratch -> visible failure, no corruption

  scale_kernel<<<dim3(24), dim3(256), 0, stream>>>(rkern, cm);
  int prep_total = W8_BYTES + WFX_ELEMS + N3;
  prep_kernel<<<dim3((prep_total + 255) / 256), dim3(256), 0, stream>>>(
      kern, rkern, bias_i, bias_r, cm, w8, wfx, bsum);
  mx_kernel<<<dim3(1600), dim3(256), 0, stream>>>(inputs, emb, wfx, bsum, MX2);
  gru_kernel<<<dim3(NG), dim3(1024), 0, stream>>>(MX2, w8, cm, bias_r, w_out, b_out, out);
}

// Round 8
// 221.770 us; speedup vs baseline: 1.4388x; 1.4388x over previous
//
#include <hip/hip_runtime.h>
#include <stdint.h>

typedef __attribute__((ext_vector_type(8))) short short8;
typedef __attribute__((ext_vector_type(4))) float f32x4;
typedef __attribute__((ext_vector_type(4))) int   i32x4;
typedef __attribute__((ext_vector_type(4))) unsigned int u32x4;

#define T_STEPS 200
#define BATCH   128
#define UNITS   256
#define N3      768
#define EMB_D   100

#define NG 32       // row groups (blocks in gru kernel)
#define RR 4        // batch rows per group
#define GWAVES 16   // waves per gru block

#define W8_BYTES  (48 * 4 * 64 * 16)         // 196608 == 256*768 i8 frags
#define WFX_ELEMS (48 * 4 * 64 * 8)          // 98304  == 128*768 bf16 (K padded 100->128)

#define NLOG2E  -1.4426950408889634f         // -log2(e), folded into z/r columns
#define N2LOG2E -2.8853900817779268f         // -2*log2(e), folded into c columns

#if __has_builtin(__builtin_amdgcn_exp2f)
#define EXP2(x) __builtin_amdgcn_exp2f(x)
#else
#define EXP2(x) __expf((x) * 0.6931471805599453f)
#endif

__device__ __forceinline__ unsigned short f2bf(float f) {
  unsigned int u = __float_as_uint(f);
  u = (u + 0x7fffu + ((u >> 16) & 1u)) >> 16;   // RNE
  return (unsigned short)u;
}
__device__ __forceinline__ float sigmoidf_(float x) {
  return __builtin_amdgcn_rcpf(1.0f + __expf(-x));
}

// ---------------- kernel 0a: per-column absmax of rkernel -> cm[768] ----------------
__global__ void scale_kernel(const float* __restrict__ rkern, float* __restrict__ cm) {
  __shared__ float red[256];
  int t = threadIdx.x;
  int n = blockIdx.x * 32 + (t & 31);
  int k0 = (t >> 5) * 32;
  float m = 0.0f;
#pragma unroll 8
  for (int k = k0; k < k0 + 32; ++k) m = fmaxf(m, fabsf(rkern[k * N3 + n]));
  red[t] = m;
  __syncthreads();
  if (t < 32) {
    float mm = red[t];
#pragma unroll
    for (int s = 1; s < 8; ++s) mm = fmaxf(mm, red[t + 32 * s]);
    cm[blockIdx.x * 32 + t] = (mm > 0.0f) ? mm : 1.0f;
  }
}

// ------- kernel 0b: quantize rkernel->i8 frags; kernel->bf16 frags (log2e-folded) ----
__global__ void prep_kernel(const float* __restrict__ kern,
                            const float* __restrict__ rkern,
                            const float* __restrict__ bias_i,
                            const float* __restrict__ bias_r,
                            const float* __restrict__ cm,
                            signed char* __restrict__ w8,
                            unsigned short* __restrict__ wfx,
                            float* __restrict__ bsum) {
  int i = blockIdx.x * 256 + threadIdx.x;
  if (i < W8_BYTES) {
    // byte i = ((ntg*4 + kc)*64 + l)*16 + e  ->  rkernel[k][n] / cm[n] * 127
    int e = i & 15, l = (i >> 4) & 63, kc = (i >> 10) & 3, ntg = i >> 12;
    int r = (e & 3) + ((l >> 4) & 3) * 4 + ((e >> 2) & 3) * 16;  // k within 64-chunk
    int k = kc * 64 + r;
    int n = ntg * 16 + (l & 15);
    float v = rintf(rkern[k * N3 + n] * 127.0f / cm[n]);
    v = fminf(127.0f, fmaxf(-127.0f, v));
    w8[i] = (signed char)(int)v;
  } else if (i < W8_BYTES + WFX_ELEMS) {
    int j = i - W8_BYTES;
    int e = j & 7, l = (j >> 3) & 63, ks = (j >> 9) & 3, nt = j >> 11;
    int k = ks * 32 + (e >> 2) * 16 + ((l >> 4) & 3) * 4 + (e & 3);
    int n = nt * 16 + (l & 15);
    float gf = (n < 2 * UNITS) ? NLOG2E : N2LOG2E;   // fold exp2 scale into columns
    wfx[j] = (k < EMB_D) ? f2bf(kern[k * N3 + n] * gf) : (unsigned short)0;
  } else if (i < W8_BYTES + WFX_ELEMS + N3) {
    int c = i - (W8_BYTES + WFX_ELEMS);
    float gf = (c < 2 * UNITS) ? NLOG2E : N2LOG2E;
    bsum[c] = (bias_i[c] + ((c < 2 * UNITS) ? bias_r[c] : 0.0f)) * gf;
  }
}

// -------- kernel 1: MX = emb[inputs] @ kernel' + bsum', packed per-thread layout -----
// MXzr[((t*32+g)*16+wv)*64+l] = z|(r<<16) bf16 pair; MXc[same] = c bf16,
// for (row = g*4 + (l>>4), u = wv*16 + (l&15)).
__global__ __launch_bounds__(256) void mx_kernel(
    const int* __restrict__ inputs, const float* __restrict__ emb,
    const unsigned short* __restrict__ wfx, const float* __restrict__ bsum,
    unsigned int* __restrict__ MXzr, unsigned short* __restrict__ MXc) {
  __shared__ unsigned short Af[4 * 64 * 8];   // 4 KB A-fragments (16 rows x K128)
  __shared__ unsigned short stg[3 * 16 * 256];// 24 KB staging [gate][row16][u]
  int tile = blockIdx.x;                      // tile == t*8 + gold  (1600 tiles)
  int tid = threadIdx.x;
  int lane = tid & 63;
  int wv = tid >> 6;
  {
    short8 z = {0, 0, 0, 0, 0, 0, 0, 0};
    ((short8*)Af)[tid] = z;
  }
  __syncthreads();
  for (int e = tid; e < 16 * EMB_D; e += 256) {
    int r = e / EMB_D;
    int c = e - r * EMB_D;
    int m = tile * 16 + r;                    // m = t*128 + b
    int ti = m >> 7, b = m & 127;
    int word = inputs[b * T_STEPS + ti];
    float v = emb[word * EMB_D + c];
    int idx = ((c >> 5) * 64 + (r + 16 * ((c >> 2) & 3))) * 8 + ((c >> 4) & 1) * 4 + (c & 3);
    Af[idx] = f2bf(v);
  }
  __syncthreads();
  short8 a0 = ((short8*)Af)[0 * 64 + lane];
  short8 a1 = ((short8*)Af)[1 * 64 + lane];
  short8 a2 = ((short8*)Af)[2 * 64 + lane];
  short8 a3 = ((short8*)Af)[3 * 64 + lane];
  int r0 = (lane >> 4) * 4;
  for (int q = 0; q < 12; ++q) {
    int nt = wv * 12 + q;
    f32x4 acc = {0.f, 0.f, 0.f, 0.f};
    const short8* bp = (const short8*)(wfx) + (nt * 4) * 64 + lane;
    acc = __builtin_amdgcn_mfma_f32_16x16x32_bf16(a0, bp[0],   acc, 0, 0, 0);
    acc = __builtin_amdgcn_mfma_f32_16x16x32_bf16(a1, bp[64],  acc, 0, 0, 0);
    acc = __builtin_amdgcn_mfma_f32_16x16x32_bf16(a2, bp[128], acc, 0, 0, 0);
    acc = __builtin_amdgcn_mfma_f32_16x16x32_bf16(a3, bp[192], acc, 0, 0, 0);
    int col = nt * 16 + (lane & 15);
    float bs = bsum[col];
    int gate = col >> 8, u = col & 255;
    int base = gate * 4096 + r0 * 256 + u;
#pragma unroll
    for (int j = 0; j < 4; ++j) stg[base + j * 256] = f2bf(acc[j] + bs);
  }
  __syncthreads();
  // repack to per-thread (z|r) u32 + c u16, coalesced global stores
  int t = tile >> 3, gold = tile & 7;
  for (int i = tid; i < 4096; i += 256) {
    int g4 = i >> 10, wvx = (i >> 6) & 15, l = i & 63;
    int rowl = g4 * 4 + (l >> 4);
    int u = wvx * 16 + (l & 15);
    unsigned int z = stg[rowl * 256 + u];
    unsigned int r = stg[4096 + rowl * 256 + u];
    unsigned int c = stg[8192 + rowl * 256 + u];
    size_t gidx = (((size_t)t * NG + gold * 4 + g4) * GWAVES + wvx) * 64 + l;
    MXzr[gidx] = z | (r << 16);
    MXc[gidx] = (unsigned short)c;
  }
}

// -------- kernel 2: block-local GRU, i8 MFMA, RR=4, in-wave LDS gate exchange --------
__global__ __launch_bounds__(1024) void gru_kernel(
    const unsigned int* __restrict__ MXzr, const unsigned short* __restrict__ MXc,
    const signed char* __restrict__ w8,
    const float* __restrict__ cm, const float* __restrict__ bias_r,
    const float* __restrict__ w_out, const float* __restrict__ b_out,
    float* __restrict__ out) {
  __shared__ i32x4 hAv[2][4 * 64];            // 8 KB: double-buffered h i8 A-frags
  __shared__ int ex[GWAVES * 192];            // 12 KB: per-wave [j][gate][s] i32 exchange
  __shared__ float hout[RR * UNITS];          // 4 KB: final h for output GEMV
  __shared__ float part[GWAVES];

  int g = blockIdx.x;                          // 0..31
  int tid = threadIdx.x;
  int lane = tid & 63;
  int wv = tid >> 6;                           // 0..15

  // persistent weights: wave wv owns ntile triple {wv, 16+wv, 32+wv}
  i32x4 bz[4], br[4], bc[4];
  {
    const i32x4* wsrc = (const i32x4*)w8 + lane;
#pragma unroll
    for (int kc = 0; kc < 4; ++kc) {
      bz[kc] = wsrc[(size_t)((wv)*4 + kc) * 64];
      br[kc] = wsrc[(size_t)((16 + wv) * 4 + kc) * 64];
      bc[kc] = wsrc[(size_t)((32 + wv) * 4 + kc) * 64];
    }
  }
  if (tid < 256) { i32x4 z = {0, 0, 0, 0}; hAv[0][tid] = z; hAv[1][tid] = z; }

  int l15 = lane & 15;
  int row = lane >> 4;                         // 0..3: this thread's gate row
  int u = wv * 16 + l15;                       // this thread's gate unit
  const float inv = 1.0f / (127.0f * 127.0f);
  float szp = cm[u] * inv * NLOG2E;
  float srp = cm[u + UNITS] * inv * NLOG2E;
  float scp = cm[u + 2 * UNITS] * inv * N2LOG2E;
  float brcp = bias_r[2 * UNITS + u] * N2LOG2E;

  // hA byte-write base for (row, u): plane kc=u>>6 (1024 B), lane la=16*((u>>2)&3)+row,
  // byte e=(u&3)+4*((u>>4)&3). Buffer stride 4096 B.
  int hwb = (u >> 6) * 1024 + (16 * ((u >> 2) & 3) + row) * 16 + (u & 3) + 4 * ((u >> 4) & 3);

  int exw = wv * 192;                          // this wave's exchange region (words)
  int exr = exw + row * 48 + l15;              // read base: [row][gate0][s]

  float h = 0.0f;
  const unsigned int* mzr = MXzr + ((size_t)g * GWAVES + wv) * 64 + lane;
  const unsigned short* mc = MXc + ((size_t)g * GWAVES + wv) * 64 + lane;
  const size_t mxstride = (size_t)NG * GWAVES * 64;
  const float MAGIC = 12582912.0f;             // 2^23 + 2^22

  __syncthreads();

  for (int t = 0; t < T_STEPS; ++t) {
    // prefetch this step's mx (consumed after barrier -> latency hidden)
    unsigned int vzr = *mzr;  mzr += mxstride;
    unsigned int vc  = *mc;   mc  += mxstride;

    const i32x4* hp = &hAv[t & 1][0];
    i32x4 af0 = hp[0 * 64 + lane];
    i32x4 af1 = hp[1 * 64 + lane];
    i32x4 af2 = hp[2 * 64 + lane];
    i32x4 af3 = hp[3 * 64 + lane];

    i32x4 az = {0, 0, 0, 0}, ar = {0, 0, 0, 0}, ac = {0, 0, 0, 0};
    az = __builtin_amdgcn_mfma_i32_16x16x64_i8(af0, bz[0], az, 0, 0, 0);
    ar = __builtin_amdgcn_mfma_i32_16x16x64_i8(af0, br[0], ar, 0, 0, 0);
    ac = __builtin_amdgcn_mfma_i32_16x16x64_i8(af0, bc[0], ac, 0, 0, 0);
    az = __builtin_amdgcn_mfma_i32_16x16x64_i8(af1, bz[1], az, 0, 0, 0);
    ar = __builtin_amdgcn_mfma_i32_16x16x64_i8(af1, br[1], ar, 0, 0, 0);
    ac = __builtin_amdgcn_mfma_i32_16x16x64_i8(af1, bc[1], ac, 0, 0, 0);
    az = __builtin_amdgcn_mfma_i32_16x16x64_i8(af2, bz[2], az, 0, 0, 0);
    ar = __builtin_amdgcn_mfma_i32_16x16x64_i8(af2, br[2], ar, 0, 0, 0);
    ac = __builtin_amdgcn_mfma_i32_16x16x64_i8(af2, bc[2], ac, 0, 0, 0);
    az = __builtin_amdgcn_mfma_i32_16x16x64_i8(af3, bz[3], az, 0, 0, 0);
    ar = __builtin_amdgcn_mfma_i32_16x16x64_i8(af3, br[3], ar, 0, 0, 0);
    ac = __builtin_amdgcn_mfma_i32_16x16x64_i8(af3, bc[3], ac, 0, 0, 0);

    // D rows 0..3 live in lanes 0..15 (r0==0); scatter to [j][gate][s], 2-way max
    if (lane < 16) {
#pragma unroll
      for (int j = 0; j < 4; ++j) {
        ex[exw + j * 48 + lane]      = az[j];
        ex[exw + j * 48 + 16 + lane] = ar[j];
        ex[exw + j * 48 + 32 + lane] = ac[j];
      }
    }
    __syncthreads();

    // gate phase: exactly one (row, u) triple per thread
    float zi = (float)ex[exr];
    float ri = (float)ex[exr + 16];
    float ci = (float)ex[exr + 32];
    float xz = __uint_as_float(vzr << 16);
    float xr = __uint_as_float(vzr & 0xffff0000u);
    float xc = __uint_as_float(((unsigned int)vc) << 16);
    float tz = 1.0f + EXP2(fminf(__fmaf_rn(zi, szp, xz), 30.0f));
    float tr = 1.0f + EXP2(fminf(__fmaf_rn(ri, srp, xr), 30.0f));
    float R  = __builtin_amdgcn_rcpf(tz * tr);
    float zg = tr * R;                          // sigmoid(z)
    float rg = tz * R;                          // sigmoid(r)
    float mcv = __fmaf_rn(ci, scp, brcp);
    float tc = 1.0f + EXP2(fminf(__fmaf_rn(rg, mcv, xc), 60.0f));
    float cand = __fmaf_rn(2.0f, __builtin_amdgcn_rcpf(tc), -1.0f);  // tanh
    h = __fmaf_rn(zg, h - cand, cand);
    float q = __fmaf_rn(h, 127.0f, MAGIC);
    ((signed char*)hAv)[(((t & 1) ^ 1) * 4096) + hwb] = (signed char)(__float_as_uint(q) & 0xFF);
    __syncthreads();
  }

  // epilogue: logits = h @ w_out + b_out -> sigmoid
  hout[row * UNITS + u] = h;
  __syncthreads();
  {
    int orow = wv >> 2;
    int uu = (wv & 3) * 64 + lane;
    float p = hout[orow * UNITS + uu] * w_out[uu];
    p += __shfl_down(p, 32, 64);
    p += __shfl_down(p, 16, 64);
    p += __shfl_down(p, 8, 64);
    p += __shfl_down(p, 4, 64);
    p += __shfl_down(p, 2, 64);
    p += __shfl_down(p, 1, 64);
    if (lane == 0) part[wv] = p;
  }
  __syncthreads();
  if (tid < RR) {
    float p = part[4 * tid] + part[4 * tid + 1] + part[4 * tid + 2] + part[4 * tid + 3];
    out[g * RR + tid] = sigmoidf_(p + b_out[0]);
  }
}

extern "C" void kernel_launch(void* const* d_in, const int* in_sizes, int n_in,
                              void* d_out, int out_size, void* d_ws, size_t ws_size,
                              hipStream_t stream) {
  const int*   inputs = (const int*)d_in[0];
  const float* emb    = (const float*)d_in[1];
  const float* kern   = (const float*)d_in[2];
  const float* rkern  = (const float*)d_in[3];
  const float* bias_i = (const float*)d_in[4];
  const float* bias_r = (const float*)d_in[5];
  const float* w_out  = (const float*)d_in[6];
  const float* b_out  = (const float*)d_in[7];
  float* out = (float*)d_out;

  char* ws = (char*)d_ws;
  size_t off = 0;
  size_t mxn = (size_t)T_STEPS * NG * GWAVES * 64;                     // 6.55M entries
  unsigned int*   MXzr = (unsigned int*)(ws + off);   off += mxn * 4;  // 26.2 MB
  unsigned short* MXc  = (unsigned short*)(ws + off); off += mxn * 2;  // 13.1 MB
  signed char*    w8   = (signed char*)(ws + off);    off += (size_t)W8_BYTES;     // 192 KB
  unsigned short* wfx  = (unsigned short*)(ws + off); off += (size_t)WFX_ELEMS * 2;// 192 KB
  float* cm   = (float*)(ws + off); off += (size_t)N3 * 4;
  float* bsum = (float*)(ws + off); off += (size_t)N3 * 4;
  if (off > ws_size) return;  // insufficient scratch -> visible failure, no corruption

  scale_kernel<<<dim3(24), dim3(256), 0, stream>>>(rkern, cm);
  int prep_total = W8_BYTES + WFX_ELEMS + N3;
  prep_kernel<<<dim3((prep_total + 255) / 256), dim3(256), 0, stream>>>(
      kern, rkern, bias_i, bias_r, cm, w8, wfx, bsum);
  mx_kernel<<<dim3(1600), dim3(256), 0, stream>>>(inputs, emb, wfx, bsum, MXzr, MXc);
  gru_kernel<<<dim3(NG), dim3(1024), 0, stream>>>(MXzr, MXc, w8, cm, bias_r, w_out, b_out, out);
}

// Round 9
// 200.159 us; speedup vs baseline: 1.5942x; 1.1080x over previous
//
#include <hip/hip_runtime.h>
#include <stdint.h>

typedef __attribute__((ext_vector_type(8))) short short8;
typedef __attribute__((ext_vector_type(4))) short short4v;
typedef __attribute__((ext_vector_type(4))) float f32x4;
typedef __attribute__((ext_vector_type(4))) int   i32x4;
typedef __attribute__((ext_vector_type(4))) unsigned int u32x4;

#define T_STEPS 200
#define BATCH   128
#define UNITS   256
#define N3      768
#define EMB_D   100

#define NG 32       // row groups (blocks in gru kernel)
#define RR 4        // batch rows per group
#define GWAVES 16   // waves per gru block

#define W8_BYTES  (48 * 4 * 64 * 16)         // 196608 == 256*768 i8 frags
#define WFX_ELEMS (48 * 4 * 64 * 8)          // 98304  == 128*768 bf16 (K padded 100->128)

#define NLOG2E  -1.4426950408889634f         // -log2(e), folded into z/r columns
#define N2LOG2E -2.8853900817779268f         // -2*log2(e), folded into c columns

#if __has_builtin(__builtin_amdgcn_exp2f)
#define EXP2(x) __builtin_amdgcn_exp2f(x)
#else
#define EXP2(x) __expf((x) * 0.6931471805599453f)
#endif

__device__ __forceinline__ unsigned short f2bf(float f) {
  unsigned int u = __float_as_uint(f);
  u = (u + 0x7fffu + ((u >> 16) & 1u)) >> 16;   // RNE
  return (unsigned short)u;
}
__device__ __forceinline__ float sigmoidf_(float x) {
  return __builtin_amdgcn_rcpf(1.0f + __expf(-x));
}

// ---------------- kernel 0a: per-column absmax of rkernel -> cm[768] ----------------
__global__ void scale_kernel(const float* __restrict__ rkern, float* __restrict__ cm) {
  __shared__ float red[256];
  int t = threadIdx.x;
  int n = blockIdx.x * 32 + (t & 31);
  int k0 = (t >> 5) * 32;
  float m = 0.0f;
#pragma unroll 8
  for (int k = k0; k < k0 + 32; ++k) m = fmaxf(m, fabsf(rkern[k * N3 + n]));
  red[t] = m;
  __syncthreads();
  if (t < 32) {
    float mm = red[t];
#pragma unroll
    for (int s = 1; s < 8; ++s) mm = fmaxf(mm, red[t + 32 * s]);
    cm[blockIdx.x * 32 + t] = (mm > 0.0f) ? mm : 1.0f;
  }
}

// ------- kernel 0b: quantize rkernel->i8 frags; kernel->bf16 frags (log2e-folded) ----
__global__ void prep_kernel(const float* __restrict__ kern,
                            const float* __restrict__ rkern,
                            const float* __restrict__ bias_i,
                            const float* __restrict__ bias_r,
                            const float* __restrict__ cm,
                            signed char* __restrict__ w8,
                            unsigned short* __restrict__ wfx,
                            float* __restrict__ bsum) {
  int i = blockIdx.x * 256 + threadIdx.x;
  if (i < W8_BYTES) {
    // byte i = ((ntg*4 + kc)*64 + l)*16 + e  ->  rkernel[k][n] / cm[n] * 127
    int e = i & 15, l = (i >> 4) & 63, kc = (i >> 10) & 3, ntg = i >> 12;
    int r = (e & 3) + ((l >> 4) & 3) * 4 + ((e >> 2) & 3) * 16;  // k within 64-chunk
    int k = kc * 64 + r;
    int n = ntg * 16 + (l & 15);
    float v = rintf(rkern[k * N3 + n] * 127.0f / cm[n]);
    v = fminf(127.0f, fmaxf(-127.0f, v));
    w8[i] = (signed char)(int)v;
  } else if (i < W8_BYTES + WFX_ELEMS) {
    int j = i - W8_BYTES;
    int e = j & 7, l = (j >> 3) & 63, ks = (j >> 9) & 3, nt = j >> 11;
    int k = ks * 32 + (e >> 2) * 16 + ((l >> 4) & 3) * 4 + (e & 3);
    int n = nt * 16 + (l & 15);
    float gf = (n < 2 * UNITS) ? NLOG2E : N2LOG2E;   // fold exp2 scale into columns
    wfx[j] = (k < EMB_D) ? f2bf(kern[k * N3 + n] * gf) : (unsigned short)0;
  } else if (i < W8_BYTES + WFX_ELEMS + N3) {
    int c = i - (W8_BYTES + WFX_ELEMS);
    float gf = (c < 2 * UNITS) ? NLOG2E : N2LOG2E;
    bsum[c] = (bias_i[c] + ((c < 2 * UNITS) ? bias_r[c] : 0.0f)) * gf;
  }
}

// -------- kernel 1: MX = emb[inputs] @ kernel' + bsum', packed per-thread layout -----
// MXzr[((t*32+g)*16+wv)*64+l] = z|(r<<16) bf16 pair; MXc[same] = c bf16,
// for (row = g*4 + (l>>4), u = wv*16 + (l&15)).
__global__ __launch_bounds__(256) void mx_kernel(
    const int* __restrict__ inputs, const float* __restrict__ emb,
    const unsigned short* __restrict__ wfx, const float* __restrict__ bsum,
    unsigned int* __restrict__ MXzr, unsigned short* __restrict__ MXc) {
  __shared__ unsigned short Af[4 * 64 * 8];   // 4 KB A-fragments (16 rows x K128)
  __shared__ unsigned short stg[3 * 16 * 256];// 24 KB staging [gate][row16][u]
  int tile = blockIdx.x;                      // tile == t*8 + gold  (1600 tiles)
  int tid = threadIdx.x;
  int lane = tid & 63;
  int wv = tid >> 6;
  {
    short8 z = {0, 0, 0, 0, 0, 0, 0, 0};
    ((short8*)Af)[tid] = z;
  }
  __syncthreads();
  // vectorized gather: 16 rows x 25 float4 chunks (emb rows 16B-aligned at c%4==0)
  for (int i = tid; i < 512; i += 256) {
    int r = i >> 5, c4 = i & 31;
    if (c4 < 25) {
      int m = tile * 16 + r;                  // m = t*128 + b
      int ti = m >> 7, b = m & 127;
      int word = inputs[b * T_STEPS + ti];
      f32x4 v = *(const f32x4*)(emb + word * EMB_D + c4 * 4);
      int c = c4 * 4;
      int idx0 = ((c >> 5) * 64 + (r + 16 * ((c >> 2) & 3))) * 8 + ((c >> 4) & 1) * 4;
      short4v p = {(short)f2bf(v.x), (short)f2bf(v.y), (short)f2bf(v.z), (short)f2bf(v.w)};
      *(short4v*)&Af[idx0] = p;               // (c&3)=0..3 are contiguous in frag order
    }
  }
  __syncthreads();
  short8 a0 = ((short8*)Af)[0 * 64 + lane];
  short8 a1 = ((short8*)Af)[1 * 64 + lane];
  short8 a2 = ((short8*)Af)[2 * 64 + lane];
  short8 a3 = ((short8*)Af)[3 * 64 + lane];
  int r0 = (lane >> 4) * 4;
  for (int q = 0; q < 12; ++q) {
    int nt = wv * 12 + q;
    f32x4 acc = {0.f, 0.f, 0.f, 0.f};
    const short8* bp = (const short8*)(wfx) + (nt * 4) * 64 + lane;
    acc = __builtin_amdgcn_mfma_f32_16x16x32_bf16(a0, bp[0],   acc, 0, 0, 0);
    acc = __builtin_amdgcn_mfma_f32_16x16x32_bf16(a1, bp[64],  acc, 0, 0, 0);
    acc = __builtin_amdgcn_mfma_f32_16x16x32_bf16(a2, bp[128], acc, 0, 0, 0);
    acc = __builtin_amdgcn_mfma_f32_16x16x32_bf16(a3, bp[192], acc, 0, 0, 0);
    int col = nt * 16 + (lane & 15);
    float bs = bsum[col];
    int gate = col >> 8, u = col & 255;
    int base = gate * 4096 + r0 * 256 + u;
#pragma unroll
    for (int j = 0; j < 4; ++j) stg[base + j * 256] = f2bf(acc[j] + bs);
  }
  __syncthreads();
  // repack to per-thread (z|r) u32 + c u16, coalesced global stores
  int t = tile >> 3, gold = tile & 7;
  for (int i = tid; i < 4096; i += 256) {
    int g4 = i >> 10, wvx = (i >> 6) & 15, l = i & 63;
    int rowl = g4 * 4 + (l >> 4);
    int u = wvx * 16 + (l & 15);
    unsigned int z = stg[rowl * 256 + u];
    unsigned int r = stg[4096 + rowl * 256 + u];
    unsigned int c = stg[8192 + rowl * 256 + u];
    size_t gidx = (((size_t)t * NG + gold * 4 + g4) * GWAVES + wvx) * 64 + l;
    MXzr[gidx] = z | (r << 16);
    MXc[gidx] = (unsigned short)c;
  }
}

// -------- kernel 2: block-local GRU, i8 MFMA, RR=4, one barrier per step -------------
__global__ __launch_bounds__(1024) void gru_kernel(
    const unsigned int* __restrict__ MXzr, const unsigned short* __restrict__ MXc,
    const signed char* __restrict__ w8,
    const float* __restrict__ cm, const float* __restrict__ bias_r,
    const float* __restrict__ w_out, const float* __restrict__ b_out,
    float* __restrict__ out) {
  __shared__ i32x4 hAv[2][4 * 64];            // 8 KB: double-buffered h i8 A-frags
  __shared__ int ex[GWAVES * 192];            // 12 KB: per-wave [j][gate][s] i32 exchange
  __shared__ float hout[RR * UNITS];          // 4 KB: final h for output GEMV
  __shared__ float part[GWAVES];

  int g = blockIdx.x;                          // 0..31
  int tid = threadIdx.x;
  int lane = tid & 63;
  int wv = tid >> 6;                           // 0..15

  // persistent weights: wave wv owns ntile triple {wv, 16+wv, 32+wv}
  i32x4 bz[4], br[4], bc[4];
  {
    const i32x4* wsrc = (const i32x4*)w8 + lane;
#pragma unroll
    for (int kc = 0; kc < 4; ++kc) {
      bz[kc] = wsrc[(size_t)((wv)*4 + kc) * 64];
      br[kc] = wsrc[(size_t)((16 + wv) * 4 + kc) * 64];
      bc[kc] = wsrc[(size_t)((32 + wv) * 4 + kc) * 64];
    }
  }
  if (tid < 256) { i32x4 z = {0, 0, 0, 0}; hAv[0][tid] = z; hAv[1][tid] = z; }

  int l15 = lane & 15;
  int row = lane >> 4;                         // 0..3: this thread's gate row
  int u = wv * 16 + l15;                       // this thread's gate unit
  const float inv = 1.0f / (127.0f * 127.0f);
  float szp = cm[u] * inv * NLOG2E;
  float srp = cm[u + UNITS] * inv * NLOG2E;
  float scp = cm[u + 2 * UNITS] * inv * N2LOG2E;
  float brcp = bias_r[2 * UNITS + u] * N2LOG2E;

  // hA byte-write base for (row, u): plane kc=u>>6 (1024 B), lane la=16*((u>>2)&3)+row,
  // byte e=(u&3)+4*((u>>4)&3). Buffer stride 4096 B.
  int hwb = (u >> 6) * 1024 + (16 * ((u >> 2) & 3) + row) * 16 + (u & 3) + 4 * ((u >> 4) & 3);

  int exw = wv * 192;                          // this wave's exchange region (words)
  int exr = exw + row * 48 + l15;              // read base: [row][gate0][s]

  float h = 0.0f;
  const unsigned int* mzr = MXzr + ((size_t)g * GWAVES + wv) * 64 + lane;
  const unsigned short* mc = MXc + ((size_t)g * GWAVES + wv) * 64 + lane;
  const size_t mxstride = (size_t)NG * GWAVES * 64;
  const float MAGIC = 12582912.0f;             // 2^23 + 2^22

  __syncthreads();

  for (int t = 0; t < T_STEPS; ++t) {
    // prefetch this step's mx (consumed late -> latency hidden)
    unsigned int vzr = *mzr;  mzr += mxstride;
    unsigned int vc  = *mc;   mc  += mxstride;

    const i32x4* hp = &hAv[t & 1][0];
    i32x4 af0 = hp[0 * 64 + lane];
    i32x4 af1 = hp[1 * 64 + lane];
    i32x4 af2 = hp[2 * 64 + lane];
    i32x4 af3 = hp[3 * 64 + lane];

    i32x4 az = {0, 0, 0, 0}, ar = {0, 0, 0, 0}, ac = {0, 0, 0, 0};
    az = __builtin_amdgcn_mfma_i32_16x16x64_i8(af0, bz[0], az, 0, 0, 0);
    ar = __builtin_amdgcn_mfma_i32_16x16x64_i8(af0, br[0], ar, 0, 0, 0);
    ac = __builtin_amdgcn_mfma_i32_16x16x64_i8(af0, bc[0], ac, 0, 0, 0);
    az = __builtin_amdgcn_mfma_i32_16x16x64_i8(af1, bz[1], az, 0, 0, 0);
    ar = __builtin_amdgcn_mfma_i32_16x16x64_i8(af1, br[1], ar, 0, 0, 0);
    ac = __builtin_amdgcn_mfma_i32_16x16x64_i8(af1, bc[1], ac, 0, 0, 0);
    az = __builtin_amdgcn_mfma_i32_16x16x64_i8(af2, bz[2], az, 0, 0, 0);
    ar = __builtin_amdgcn_mfma_i32_16x16x64_i8(af2, br[2], ar, 0, 0, 0);
    ac = __builtin_amdgcn_mfma_i32_16x16x64_i8(af2, bc[2], ac, 0, 0, 0);
    az = __builtin_amdgcn_mfma_i32_16x16x64_i8(af3, bz[3], az, 0, 0, 0);
    ar = __builtin_amdgcn_mfma_i32_16x16x64_i8(af3, br[3], ar, 0, 0, 0);
    ac = __builtin_amdgcn_mfma_i32_16x16x64_i8(af3, bc[3], ac, 0, 0, 0);

    // D rows 0..3 live in lanes 0..15; scatter to per-WAVE region -> intra-wave
    // exchange: ds ordering (lgkmcnt) suffices, NO __syncthreads needed.
    if (lane < 16) {
#pragma unroll
      for (int j = 0; j < 4; ++j) {
        ex[exw + j * 48 + lane]      = az[j];
        ex[exw + j * 48 + 16 + lane] = ar[j];
        ex[exw + j * 48 + 32 + lane] = ac[j];
      }
    }

    // gate phase: exactly one (row, u) triple per thread
    float zi = (float)ex[exr];
    float ri = (float)ex[exr + 16];
    float ci = (float)ex[exr + 32];
    float xz = __uint_as_float(vzr << 16);
    float xr = __uint_as_float(vzr & 0xffff0000u);
    float xc = __uint_as_float(((unsigned int)vc) << 16);
    float tz = 1.0f + EXP2(fminf(__fmaf_rn(zi, szp, xz), 30.0f));
    float tr = 1.0f + EXP2(fminf(__fmaf_rn(ri, srp, xr), 30.0f));
    float R  = __builtin_amdgcn_rcpf(tz * tr);
    float zg = tr * R;                          // sigmoid(z)
    float rg = tz * R;                          // sigmoid(r)
    float mcv = __fmaf_rn(ci, scp, brcp);
    float tc = 1.0f + EXP2(fminf(__fmaf_rn(rg, mcv, xc), 60.0f));
    float cand = __fmaf_rn(2.0f, __builtin_amdgcn_rcpf(tc), -1.0f);  // tanh
    h = __fmaf_rn(zg, h - cand, cand);
    float q = __fmaf_rn(h, 127.0f, MAGIC);
    ((signed char*)hAv)[(((t & 1) ^ 1) * 4096) + hwb] = (signed char)(__float_as_uint(q) & 0xFF);
    // single barrier/step: step t reads hAv[t&1] BEFORE it; step t+1 writes
    // hAv[t&1] AFTER it -> ping-pong is hazard-free with one barrier.
    __syncthreads();
  }

  // epilogue: logits = h @ w_out + b_out -> sigmoid
  hout[row * UNITS + u] = h;
  __syncthreads();
  {
    int orow = wv >> 2;
    int uu = (wv & 3) * 64 + lane;
    float p = hout[orow * UNITS + uu] * w_out[uu];
    p += __shfl_down(p, 32, 64);
    p += __shfl_down(p, 16, 64);
    p += __shfl_down(p, 8, 64);
    p += __shfl_down(p, 4, 64);
    p += __shfl_down(p, 2, 64);
    p += __shfl_down(p, 1, 64);
    if (lane == 0) part[wv] = p;
  }
  __syncthreads();
  if (tid < RR) {
    float p = part[4 * tid] + part[4 * tid + 1] + part[4 * tid + 2] + part[4 * tid + 3];
    out[g * RR + tid] = sigmoidf_(p + b_out[0]);
  }
}

extern "C" void kernel_launch(void* const* d_in, const int* in_sizes, int n_in,
                              void* d_out, int out_size, void* d_ws, size_t ws_size,
                              hipStream_t stream) {
  const int*   inputs = (const int*)d_in[0];
  const float* emb    = (const float*)d_in[1];
  const float* kern   = (const float*)d_in[2];
  const float* rkern  = (const float*)d_in[3];
  const float* bias_i = (const float*)d_in[4];
  const float* bias_r = (const float*)d_in[5];
  const float* w_out  = (const float*)d_in[6];
  const float* b_out  = (const float*)d_in[7];
  float* out = (float*)d_out;

  char* ws = (char*)d_ws;
  size_t off = 0;
  size_t mxn = (size_t)T_STEPS * NG * GWAVES * 64;                     // 6.55M entries
  unsigned int*   MXzr = (unsigned int*)(ws + off);   off += mxn * 4;  // 26.2 MB
  unsigned short* MXc  = (unsigned short*)(ws + off); off += mxn * 2;  // 13.1 MB
  signed char*    w8   = (signed char*)(ws + off);    off += (size_t)W8_BYTES;     // 192 KB
  unsigned short* wfx  = (unsigned short*)(ws + off); off += (size_t)WFX_ELEMS * 2;// 192 KB
  float* cm   = (float*)(ws + off); off += (size_t)N3 * 4;
  float* bsum = (float*)(ws + off); off += (size_t)N3 * 4;
  if (off > ws_size) return;  // insufficient scratch -> visible failure, no corruption

  scale_kernel<<<dim3(24), dim3(256), 0, stream>>>(rkern, cm);
  int prep_total = W8_BYTES + WFX_ELEMS + N3;
  prep_kernel<<<dim3((prep_total + 255) / 256), dim3(256), 0, stream>>>(
      kern, rkern, bias_i, bias_r, cm, w8, wfx, bsum);
  mx_kernel<<<dim3(1600), dim3(256), 0, stream>>>(inputs, emb, wfx, bsum, MXzr, MXc);
  gru_kernel<<<dim3(NG), dim3(1024), 0, stream>>>(MXzr, MXc, w8, cm, bias_r, w_out, b_out, out);
}

// Round 10
// 191.174 us; speedup vs baseline: 1.6691x; 1.0470x over previous
//
#include <hip/hip_runtime.h>
#include <stdint.h>

typedef __attribute__((ext_vector_type(8))) short short8;
typedef __attribute__((ext_vector_type(4))) short short4v;
typedef __attribute__((ext_vector_type(4))) float f32x4;
typedef __attribute__((ext_vector_type(4))) int   i32x4;
typedef __attribute__((ext_vector_type(4))) unsigned int u32x4;

#define T_STEPS 200
#define BATCH   128
#define UNITS   256
#define N3      768
#define EMB_D   100

#define NG 32       // row groups (blocks in gru kernel)
#define RR 4        // batch rows per group
#define GWAVES 16   // waves per gru block

#define W8_BYTES  (48 * 4 * 64 * 16)         // 196608 == 256*768 i8 frags
#define WFX_ELEMS (48 * 4 * 64 * 8)          // 98304  == 128*768 bf16 (K padded 100->128)

#define NLOG2E  -1.4426950408889634f         // -log2(e), folded into z/r columns
#define N2LOG2E -2.8853900817779268f         // -2*log2(e), folded into c columns

#if __has_builtin(__builtin_amdgcn_exp2f)
#define EXP2(x) __builtin_amdgcn_exp2f(x)
#else
#define EXP2(x) __expf((x) * 0.6931471805599453f)
#endif

__device__ __forceinline__ unsigned short f2bf(float f) {
  unsigned int u = __float_as_uint(f);
  u = (u + 0x7fffu + ((u >> 16) & 1u)) >> 16;   // RNE
  return (unsigned short)u;
}
__device__ __forceinline__ float sigmoidf_(float x) {
  return __builtin_amdgcn_rcpf(1.0f + __expf(-x));
}

// ------- kernel 0: fused per-column absmax + i8 quant; kernel->bf16 frags; bsum ------
// blocks 0..47: ntg=b -> compute cm[ntg*16..+16] (LDS reduce) then quantize the
// 4096-byte w8 tile with 16B stores.  blocks 48..: wfx / bsum (1 elem/thread).
__global__ void prep_kernel(const float* __restrict__ kern,
                            const float* __restrict__ rkern,
                            const float* __restrict__ bias_i,
                            const float* __restrict__ bias_r,
                            signed char* __restrict__ w8,
                            unsigned short* __restrict__ wfx,
                            float* __restrict__ bsum,
                            float* __restrict__ cm) {
  int b = blockIdx.x;
  int tid = threadIdx.x;
  if (b < 48) {
    __shared__ float red[256];
    __shared__ float cmv[16];
    int ntg = b;
    int col = tid & 15;
    int n = ntg * 16 + col;
    int k0 = (tid >> 4) * 16;
    float m = 0.0f;
#pragma unroll 4
    for (int k = k0; k < k0 + 16; ++k) m = fmaxf(m, fabsf(rkern[k * N3 + n]));
    red[tid] = m;
    __syncthreads();
    if (tid < 16) {
      float mm = red[tid];
#pragma unroll
      for (int s = 1; s < 16; ++s) mm = fmaxf(mm, red[tid + 16 * s]);
      mm = (mm > 0.0f) ? mm : 1.0f;
      cmv[tid] = mm;
      cm[n] = mm;                           // n == ntg*16 + tid here
    }
    __syncthreads();
    // quantize: thread tid -> bytes [ntg*4096 + tid*16, +16)
    int l = tid & 63, kc = tid >> 6;
    int nn = ntg * 16 + (l & 15);
    float inv127 = 127.0f / cmv[l & 15];
    union { signed char c[16]; i32x4 v; } pk;
#pragma unroll
    for (int e = 0; e < 16; ++e) {
      int k = kc * 64 + (e & 3) + ((l >> 4) & 3) * 4 + ((e >> 2) & 3) * 16;
      float v = rintf(rkern[k * N3 + nn] * inv127);
      v = fminf(127.0f, fmaxf(-127.0f, v));
      pk.c[e] = (signed char)(int)v;
    }
    *(i32x4*)&w8[ntg * 4096 + tid * 16] = pk.v;
  } else {
    int i = (b - 48) * 256 + tid;
    if (i < WFX_ELEMS) {
      int e = i & 7, l = (i >> 3) & 63, ks = (i >> 9) & 3, nt = i >> 11;
      int k = ks * 32 + (e >> 2) * 16 + ((l >> 4) & 3) * 4 + (e & 3);
      int n = nt * 16 + (l & 15);
      float gf = (n < 2 * UNITS) ? NLOG2E : N2LOG2E; // fold exp2 scale into columns
      wfx[i] = (k < EMB_D) ? f2bf(kern[k * N3 + n] * gf) : (unsigned short)0;
    } else if (i < WFX_ELEMS + N3) {
      int c = i - WFX_ELEMS;
      float gf = (c < 2 * UNITS) ? NLOG2E : N2LOG2E;
      bsum[c] = (bias_i[c] + ((c < 2 * UNITS) ? bias_r[c] : 0.0f)) * gf;
    }
  }
}

// -------- kernel 1: MX = emb[inputs] @ kernel' + bsum', packed per-thread layout -----
// MXzr[((t*32+g)*16+wv)*64+l] = z|(r<<16) bf16 pair; MXc[same] = c bf16,
// for (row = g*4 + (l>>4), u = wv*16 + (l&15)).
__global__ __launch_bounds__(256) void mx_kernel(
    const int* __restrict__ inputs, const float* __restrict__ emb,
    const unsigned short* __restrict__ wfx, const float* __restrict__ bsum,
    unsigned int* __restrict__ MXzr, unsigned short* __restrict__ MXc) {
  __shared__ unsigned short Af[4 * 64 * 8];   // 4 KB A-fragments (16 rows x K128)
  __shared__ unsigned short stg[3 * 16 * 256];// 24 KB staging [gate][row16][u]
  int tile = blockIdx.x;                      // tile == t*8 + gold  (1600 tiles)
  int tid = threadIdx.x;
  int lane = tid & 63;
  int wv = tid >> 6;
  {
    short8 z = {0, 0, 0, 0, 0, 0, 0, 0};
    ((short8*)Af)[tid] = z;
  }
  __syncthreads();
  // vectorized gather: 16 rows x 25 float4 chunks (emb rows 16B-aligned at c%4==0)
  for (int i = tid; i < 512; i += 256) {
    int r = i >> 5, c4 = i & 31;
    if (c4 < 25) {
      int m = tile * 16 + r;                  // m = t*128 + b
      int ti = m >> 7, b = m & 127;
      int word = inputs[b * T_STEPS + ti];
      f32x4 v = *(const f32x4*)(emb + word * EMB_D + c4 * 4);
      int c = c4 * 4;
      int idx0 = ((c >> 5) * 64 + (r + 16 * ((c >> 2) & 3))) * 8 + ((c >> 4) & 1) * 4;
      short4v p = {(short)f2bf(v.x), (short)f2bf(v.y), (short)f2bf(v.z), (short)f2bf(v.w)};
      *(short4v*)&Af[idx0] = p;               // (c&3)=0..3 are contiguous in frag order
    }
  }
  __syncthreads();
  short8 a0 = ((short8*)Af)[0 * 64 + lane];
  short8 a1 = ((short8*)Af)[1 * 64 + lane];
  short8 a2 = ((short8*)Af)[2 * 64 + lane];
  short8 a3 = ((short8*)Af)[3 * 64 + lane];
  int r0 = (lane >> 4) * 4;
  for (int q = 0; q < 12; ++q) {
    int nt = wv * 12 + q;
    f32x4 acc = {0.f, 0.f, 0.f, 0.f};
    const short8* bp = (const short8*)(wfx) + (nt * 4) * 64 + lane;
    acc = __builtin_amdgcn_mfma_f32_16x16x32_bf16(a0, bp[0],   acc, 0, 0, 0);
    acc = __builtin_amdgcn_mfma_f32_16x16x32_bf16(a1, bp[64],  acc, 0, 0, 0);
    acc = __builtin_amdgcn_mfma_f32_16x16x32_bf16(a2, bp[128], acc, 0, 0, 0);
    acc = __builtin_amdgcn_mfma_f32_16x16x32_bf16(a3, bp[192], acc, 0, 0, 0);
    int col = nt * 16 + (lane & 15);
    float bs = bsum[col];
    int gate = col >> 8, u = col & 255;
    int base = gate * 4096 + r0 * 256 + u;
#pragma unroll
    for (int j = 0; j < 4; ++j) stg[base + j * 256] = f2bf(acc[j] + bs);
  }
  __syncthreads();
  // repack to per-thread (z|r) u32 + c u16, coalesced global stores
  int t = tile >> 3, gold = tile & 7;
  for (int i = tid; i < 4096; i += 256) {
    int g4 = i >> 10, wvx = (i >> 6) & 15, l = i & 63;
    int rowl = g4 * 4 + (l >> 4);
    int u = wvx * 16 + (l & 15);
    unsigned int z = stg[rowl * 256 + u];
    unsigned int r = stg[4096 + rowl * 256 + u];
    unsigned int c = stg[8192 + rowl * 256 + u];
    size_t gidx = (((size_t)t * NG + gold * 4 + g4) * GWAVES + wvx) * 64 + l;
    MXzr[gidx] = z | (r << 16);
    MXc[gidx] = (unsigned short)c;
  }
}

// -------- kernel 2: block-local GRU, i8 MFMA, 1 barrier/step, MX reg-prefetch --------
__global__ __launch_bounds__(1024) void gru_kernel(
    const unsigned int* __restrict__ MXzr, const unsigned short* __restrict__ MXc,
    const signed char* __restrict__ w8,
    const float* __restrict__ cm, const float* __restrict__ bias_r,
    const float* __restrict__ w_out, const float* __restrict__ b_out,
    float* __restrict__ out) {
  __shared__ i32x4 hAv[2][4 * 64];            // 8 KB: double-buffered h i8 A-frags
  __shared__ int ex[GWAVES * 192];            // 12 KB: per-wave [j][gate][s] i32 exchange
  __shared__ float hout[RR * UNITS];          // 4 KB: final h for output GEMV
  __shared__ float part[GWAVES];

  int g = blockIdx.x;                          // 0..31
  int tid = threadIdx.x;
  int lane = tid & 63;
  int wv = tid >> 6;                           // 0..15

  // persistent weights: wave wv owns ntile triple {wv, 16+wv, 32+wv}
  i32x4 bz[4], br[4], bc[4];
  {
    const i32x4* wsrc = (const i32x4*)w8 + lane;
#pragma unroll
    for (int kc = 0; kc < 4; ++kc) {
      bz[kc] = wsrc[(size_t)((wv)*4 + kc) * 64];
      br[kc] = wsrc[(size_t)((16 + wv) * 4 + kc) * 64];
      bc[kc] = wsrc[(size_t)((32 + wv) * 4 + kc) * 64];
    }
  }
  if (tid < 256) { i32x4 z = {0, 0, 0, 0}; hAv[0][tid] = z; hAv[1][tid] = z; }

  int l15 = lane & 15;
  int row = lane >> 4;                         // 0..3: this thread's gate row
  int u = wv * 16 + l15;                       // this thread's gate unit
  const float inv = 1.0f / (127.0f * 127.0f);
  float szp = cm[u] * inv * NLOG2E;
  float srp = cm[u + UNITS] * inv * NLOG2E;
  float scp = cm[u + 2 * UNITS] * inv * N2LOG2E;
  float brcp = bias_r[2 * UNITS + u] * N2LOG2E;

  // hA byte-write base for (row, u): plane kc=u>>6 (1024 B), lane la=16*((u>>2)&3)+row,
  // byte e=(u&3)+4*((u>>4)&3). Buffer stride 4096 B.
  int hwb = (u >> 6) * 1024 + (16 * ((u >> 2) & 3) + row) * 16 + (u & 3) + 4 * ((u >> 4) & 3);

  int exw = wv * 192;                          // this wave's exchange region (words)
  int exr = exw + row * 48 + l15;              // read base: [row][gate0][s]

  float h = 0.0f;
  const unsigned int* mzr = MXzr + ((size_t)g * GWAVES + wv) * 64 + lane;
  const unsigned short* mc = MXc + ((size_t)g * GWAVES + wv) * 64 + lane;
  const size_t mxstride = (size_t)NG * GWAVES * 64;
  const float MAGIC = 12582912.0f;             // 2^23 + 2^22

  // prefetch t=0 (consumed in step 0's gate phase; t=1 fetch issued at step-0 top)
  unsigned int vzr = *mzr;  mzr += mxstride;
  unsigned int vc  = *mc;   mc  += mxstride;

  __syncthreads();

  for (int t = 0; t < T_STEPS; ++t) {
    // issue NEXT step's mx loads now; consumed one full step later (~2000 cyc)
    // -> HBM latency fully hidden. Final iteration reads one slot past MX
    // (still inside d_ws, value unused).
    unsigned int nzr = *mzr;  mzr += mxstride;
    unsigned int nc  = *mc;   mc  += mxstride;

    const i32x4* hp = &hAv[t & 1][0];
    i32x4 af0 = hp[0 * 64 + lane];
    i32x4 af1 = hp[1 * 64 + lane];
    i32x4 af2 = hp[2 * 64 + lane];
    i32x4 af3 = hp[3 * 64 + lane];

    i32x4 az = {0, 0, 0, 0}, ar = {0, 0, 0, 0}, ac = {0, 0, 0, 0};
    az = __builtin_amdgcn_mfma_i32_16x16x64_i8(af0, bz[0], az, 0, 0, 0);
    ar = __builtin_amdgcn_mfma_i32_16x16x64_i8(af0, br[0], ar, 0, 0, 0);
    ac = __builtin_amdgcn_mfma_i32_16x16x64_i8(af0, bc[0], ac, 0, 0, 0);
    az = __builtin_amdgcn_mfma_i32_16x16x64_i8(af1, bz[1], az, 0, 0, 0);
    ar = __builtin_amdgcn_mfma_i32_16x16x64_i8(af1, br[1], ar, 0, 0, 0);
    ac = __builtin_amdgcn_mfma_i32_16x16x64_i8(af1, bc[1], ac, 0, 0, 0);
    az = __builtin_amdgcn_mfma_i32_16x16x64_i8(af2, bz[2], az, 0, 0, 0);
    ar = __builtin_amdgcn_mfma_i32_16x16x64_i8(af2, br[2], ar, 0, 0, 0);
    ac = __builtin_amdgcn_mfma_i32_16x16x64_i8(af2, bc[2], ac, 0, 0, 0);
    az = __builtin_amdgcn_mfma_i32_16x16x64_i8(af3, bz[3], az, 0, 0, 0);
    ar = __builtin_amdgcn_mfma_i32_16x16x64_i8(af3, br[3], ar, 0, 0, 0);
    ac = __builtin_amdgcn_mfma_i32_16x16x64_i8(af3, bc[3], ac, 0, 0, 0);

    // D rows 0..3 live in lanes 0..15; scatter to per-WAVE region (intra-wave
    // exchange; wave_barrier pins the ds_write -> ds_read order for the compiler)
    if (lane < 16) {
#pragma unroll
      for (int j = 0; j < 4; ++j) {
        ex[exw + j * 48 + lane]      = az[j];
        ex[exw + j * 48 + 16 + lane] = ar[j];
        ex[exw + j * 48 + 32 + lane] = ac[j];
      }
    }
#if __has_builtin(__builtin_amdgcn_wave_barrier)
    __builtin_amdgcn_wave_barrier();
#endif

    // gate phase: exactly one (row, u) triple per thread
    float zi = (float)ex[exr];
    float ri = (float)ex[exr + 16];
    float ci = (float)ex[exr + 32];
    float xz = __uint_as_float(vzr << 16);
    float xr = __uint_as_float(vzr & 0xffff0000u);
    float xc = __uint_as_float(((unsigned int)vc) << 16);
    float tz = 1.0f + EXP2(fminf(__fmaf_rn(zi, szp, xz), 30.0f));
    float tr = 1.0f + EXP2(fminf(__fmaf_rn(ri, srp, xr), 30.0f));
    float R  = __builtin_amdgcn_rcpf(tz * tr);
    float zg = tr * R;                          // sigmoid(z)
    float rg = tz * R;                          // sigmoid(r)
    float mcv = __fmaf_rn(ci, scp, brcp);
    float tc = 1.0f + EXP2(fminf(__fmaf_rn(rg, mcv, xc), 60.0f));
    float cand = __fmaf_rn(2.0f, __builtin_amdgcn_rcpf(tc), -1.0f);  // tanh
    h = __fmaf_rn(zg, h - cand, cand);
    float q = __fmaf_rn(h, 127.0f, MAGIC);
    ((signed char*)hAv)[(((t & 1) ^ 1) * 4096) + hwb] = (signed char)(__float_as_uint(q) & 0xFF);
    vzr = nzr;
    vc  = nc;
    // single barrier/step: step t reads hAv[t&1] BEFORE it; step t+1 writes
    // hAv[t&1] AFTER it -> ping-pong is hazard-free with one barrier.
    __syncthreads();
  }

  // epilogue: logits = h @ w_out + b_out -> sigmoid
  hout[row * UNITS + u] = h;
  __syncthreads();
  {
    int orow = wv >> 2;
    int uu = (wv & 3) * 64 + lane;
    float p = hout[orow * UNITS + uu] * w_out[uu];
    p += __shfl_down(p, 32, 64);
    p += __shfl_down(p, 16, 64);
    p += __shfl_down(p, 8, 64);
    p += __shfl_down(p, 4, 64);
    p += __shfl_down(p, 2, 64);
    p += __shfl_down(p, 1, 64);
    if (lane == 0) part[wv] = p;
  }
  __syncthreads();
  if (tid < RR) {
    float p = part[4 * tid] + part[4 * tid + 1] + part[4 * tid + 2] + part[4 * tid + 3];
    out[g * RR + tid] = sigmoidf_(p + b_out[0]);
  }
}

extern "C" void kernel_launch(void* const* d_in, const int* in_sizes, int n_in,
                              void* d_out, int out_size, void* d_ws, size_t ws_size,
                              hipStream_t stream) {
  const int*   inputs = (const int*)d_in[0];
  const float* emb    = (const float*)d_in[1];
  const float* kern   = (const float*)d_in[2];
  const float* rkern  = (const float*)d_in[3];
  const float* bias_i = (const float*)d_in[4];
  const float* bias_r = (const float*)d_in[5];
  const float* w_out  = (const float*)d_in[6];
  const float* b_out  = (const float*)d_in[7];
  float* out = (float*)d_out;

  char* ws = (char*)d_ws;
  size_t off = 0;
  size_t mxn = (size_t)T_STEPS * NG * GWAVES * 64;                     // 6.55M entries
  unsigned int*   MXzr = (unsigned int*)(ws + off);   off += mxn * 4;  // 26.2 MB
  unsigned short* MXc  = (unsigned short*)(ws + off); off += mxn * 2;  // 13.1 MB
  signed char*    w8   = (signed char*)(ws + off);    off += (size_t)W8_BYTES;     // 192 KB
  unsigned short* wfx  = (unsigned short*)(ws + off); off += (size_t)WFX_ELEMS * 2;// 192 KB
  float* cm   = (float*)(ws + off); off += (size_t)N3 * 4;
  float* bsum = (float*)(ws + off); off += (size_t)N3 * 4;
  if (off > ws_size) return;  // insufficient scratch -> visible failure, no corruption

  int prep_blocks = 48 + (WFX_ELEMS + N3 + 255) / 256;
  prep_kernel<<<dim3(prep_blocks), dim3(256), 0, stream>>>(
      kern, rkern, bias_i, bias_r, w8, wfx, bsum, cm);
  mx_kernel<<<dim3(1600), dim3(256), 0, stream>>>(inputs, emb, wfx, bsum, MXzr, MXc);
  gru_kernel<<<dim3(NG), dim3(1024), 0, stream>>>(MXzr, MXc, w8, cm, bias_r, w_out, b_out, out);
}

// Round 11
// 151.746 us; speedup vs baseline: 2.1028x; 1.2598x over previous
//
#include <hip/hip_runtime.h>
#include <stdint.h>

typedef __attribute__((ext_vector_type(8))) short short8;
typedef __attribute__((ext_vector_type(4))) short short4v;
typedef __attribute__((ext_vector_type(4))) float f32x4;
typedef __attribute__((ext_vector_type(4))) int   i32x4;
typedef __attribute__((ext_vector_type(4))) unsigned int u32x4;

#define T_STEPS 200
#define BATCH   128
#define UNITS   256
#define N3      768
#define EMB_D   100

#define NG 128      // one block per batch row
#define GWAVES 16   // waves per gru block

#define W8_BYTES  (48 * 4 * 64 * 16)         // 196608 == 256*768 i8 frags
#define WFX_ELEMS (48 * 4 * 64 * 8)          // 98304  == 128*768 bf16 (K padded 100->128)

#define NLOG2E  -1.4426950408889634f         // -log2(e), folded into z/r columns
#define N2LOG2E -2.8853900817779268f         // -2*log2(e), folded into c columns

#if __has_builtin(__builtin_amdgcn_exp2f)
#define EXP2(x) __builtin_amdgcn_exp2f(x)
#else
#define EXP2(x) __expf((x) * 0.6931471805599453f)
#endif

__device__ __forceinline__ unsigned short f2bf(float f) {
  unsigned int u = __float_as_uint(f);
  u = (u + 0x7fffu + ((u >> 16) & 1u)) >> 16;   // RNE
  return (unsigned short)u;
}
__device__ __forceinline__ float sigmoidf_(float x) {
  return __builtin_amdgcn_rcpf(1.0f + __expf(-x));
}

// ------- kernel 0: fused per-column absmax + i8 quant; kernel->bf16 frags; bsum ------
__global__ void prep_kernel(const float* __restrict__ kern,
                            const float* __restrict__ rkern,
                            const float* __restrict__ bias_i,
                            const float* __restrict__ bias_r,
                            signed char* __restrict__ w8,
                            unsigned short* __restrict__ wfx,
                            float* __restrict__ bsum,
                            float* __restrict__ cm) {
  int b = blockIdx.x;
  int tid = threadIdx.x;
  if (b < 48) {
    __shared__ float red[256];
    __shared__ float cmv[16];
    int ntg = b;
    int col = tid & 15;
    int n = ntg * 16 + col;
    int k0 = (tid >> 4) * 16;
    float m = 0.0f;
#pragma unroll 4
    for (int k = k0; k < k0 + 16; ++k) m = fmaxf(m, fabsf(rkern[k * N3 + n]));
    red[tid] = m;
    __syncthreads();
    if (tid < 16) {
      float mm = red[tid];
#pragma unroll
      for (int s = 1; s < 16; ++s) mm = fmaxf(mm, red[tid + 16 * s]);
      mm = (mm > 0.0f) ? mm : 1.0f;
      cmv[tid] = mm;
      cm[n] = mm;                           // n == ntg*16 + tid here
    }
    __syncthreads();
    // quantize: thread tid -> bytes [ntg*4096 + tid*16, +16)
    int l = tid & 63, kc = tid >> 6;
    int nn = ntg * 16 + (l & 15);
    float inv127 = 127.0f / cmv[l & 15];
    union { signed char c[16]; i32x4 v; } pk;
#pragma unroll
    for (int e = 0; e < 16; ++e) {
      int k = kc * 64 + (e & 3) + ((l >> 4) & 3) * 4 + ((e >> 2) & 3) * 16;
      float v = rintf(rkern[k * N3 + nn] * inv127);
      v = fminf(127.0f, fmaxf(-127.0f, v));
      pk.c[e] = (signed char)(int)v;
    }
    *(i32x4*)&w8[ntg * 4096 + tid * 16] = pk.v;
  } else {
    int i = (b - 48) * 256 + tid;
    if (i < WFX_ELEMS) {
      int e = i & 7, l = (i >> 3) & 63, ks = (i >> 9) & 3, nt = i >> 11;
      int k = ks * 32 + (e >> 2) * 16 + ((l >> 4) & 3) * 4 + (e & 3);
      int n = nt * 16 + (l & 15);
      float gf = (n < 2 * UNITS) ? NLOG2E : N2LOG2E; // fold exp2 scale into columns
      wfx[i] = (k < EMB_D) ? f2bf(kern[k * N3 + n] * gf) : (unsigned short)0;
    } else if (i < WFX_ELEMS + N3) {
      int c = i - WFX_ELEMS;
      float gf = (c < 2 * UNITS) ? NLOG2E : N2LOG2E;
      bsum[c] = (bias_i[c] + ((c < 2 * UNITS) ? bias_r[c] : 0.0f)) * gf;
    }
  }
}

// -------- kernel 1: MX = emb[inputs] @ kernel' + bsum', row-major packed -------------
// MXzr[m*256+u] = z|(r<<16) bf16 pair; MXc[m*256+u] = c bf16, m = t*128 + b.
__global__ __launch_bounds__(256) void mx_kernel(
    const int* __restrict__ inputs, const float* __restrict__ emb,
    const unsigned short* __restrict__ wfx, const float* __restrict__ bsum,
    unsigned int* __restrict__ MXzr, unsigned short* __restrict__ MXc) {
  __shared__ unsigned short Af[4 * 64 * 8];   // 4 KB A-fragments (16 rows x K128)
  __shared__ unsigned short stg[3 * 16 * 256];// 24 KB staging [gate][row16][u]
  int tile = blockIdx.x;                      // 1600 tiles of 16 m-rows
  int tid = threadIdx.x;
  int lane = tid & 63;
  int wv = tid >> 6;
  {
    short8 z = {0, 0, 0, 0, 0, 0, 0, 0};
    ((short8*)Af)[tid] = z;
  }
  __syncthreads();
  // vectorized gather: 16 rows x 25 float4 chunks (emb rows 16B-aligned at c%4==0)
  for (int i = tid; i < 512; i += 256) {
    int r = i >> 5, c4 = i & 31;
    if (c4 < 25) {
      int m = tile * 16 + r;                  // m = t*128 + b
      int ti = m >> 7, b = m & 127;
      int word = inputs[b * T_STEPS + ti];
      f32x4 v = *(const f32x4*)(emb + word * EMB_D + c4 * 4);
      int c = c4 * 4;
      int idx0 = ((c >> 5) * 64 + (r + 16 * ((c >> 2) & 3))) * 8 + ((c >> 4) & 1) * 4;
      short4v p = {(short)f2bf(v.x), (short)f2bf(v.y), (short)f2bf(v.z), (short)f2bf(v.w)};
      *(short4v*)&Af[idx0] = p;               // (c&3)=0..3 are contiguous in frag order
    }
  }
  __syncthreads();
  short8 a0 = ((short8*)Af)[0 * 64 + lane];
  short8 a1 = ((short8*)Af)[1 * 64 + lane];
  short8 a2 = ((short8*)Af)[2 * 64 + lane];
  short8 a3 = ((short8*)Af)[3 * 64 + lane];
  int r0 = (lane >> 4) * 4;
  for (int q = 0; q < 12; ++q) {
    int nt = wv * 12 + q;
    f32x4 acc = {0.f, 0.f, 0.f, 0.f};
    const short8* bp = (const short8*)(wfx) + (nt * 4) * 64 + lane;
    acc = __builtin_amdgcn_mfma_f32_16x16x32_bf16(a0, bp[0],   acc, 0, 0, 0);
    acc = __builtin_amdgcn_mfma_f32_16x16x32_bf16(a1, bp[64],  acc, 0, 0, 0);
    acc = __builtin_amdgcn_mfma_f32_16x16x32_bf16(a2, bp[128], acc, 0, 0, 0);
    acc = __builtin_amdgcn_mfma_f32_16x16x32_bf16(a3, bp[192], acc, 0, 0, 0);
    int col = nt * 16 + (lane & 15);
    float bs = bsum[col];
    int gate = col >> 8, u = col & 255;
    int base = gate * 4096 + r0 * 256 + u;
#pragma unroll
    for (int j = 0; j < 4; ++j) stg[base + j * 256] = f2bf(acc[j] + bs);
  }
  __syncthreads();
  // repack: row-major (m, u), coalesced over u
  for (int i = tid; i < 4096; i += 256) {
    int r = i >> 8, u = i & 255;
    size_t m = (size_t)tile * 16 + r;
    unsigned int z = stg[r * 256 + u];
    unsigned int rr = stg[4096 + r * 256 + u];
    unsigned int c = stg[8192 + r * 256 + u];
    MXzr[m * 256 + u] = z | (rr << 16);
    MXc[m * 256 + u] = (unsigned short)c;
  }
}

// -------- kernel 2: RR=1 — gates straight off accumulators, no LDS exchange ----------
__global__ __launch_bounds__(1024) void gru_kernel(
    const unsigned int* __restrict__ MXzr, const unsigned short* __restrict__ MXc,
    const signed char* __restrict__ w8,
    const float* __restrict__ cm, const float* __restrict__ bias_r,
    const float* __restrict__ w_out, const float* __restrict__ b_out,
    float* __restrict__ out) {
  __shared__ i32x4 hAv[2][4 * 64];            // 8 KB: double-buffered h i8 A-frags (row 0 only)
  __shared__ float hout[UNITS];               // 1 KB: final h for output GEMV

  int g = blockIdx.x;                          // batch row 0..127
  int tid = threadIdx.x;
  int lane = tid & 63;
  int wv = tid >> 6;                           // 0..15

  // persistent weights: wave wv owns gate-aligned ntile triple {wv, 16+wv, 32+wv}
  i32x4 bz[4], br[4], bc[4];
  {
    const i32x4* wsrc = (const i32x4*)w8 + lane;
#pragma unroll
    for (int kc = 0; kc < 4; ++kc) {
      bz[kc] = wsrc[(size_t)((wv)*4 + kc) * 64];
      br[kc] = wsrc[(size_t)((16 + wv) * 4 + kc) * 64];
      bc[kc] = wsrc[(size_t)((32 + wv) * 4 + kc) * 64];
    }
  }
  if (tid < 512) { i32x4 z = {0, 0, 0, 0}; ((i32x4*)hAv)[tid] = z; }

  int l15 = lane & 15;
  int u = wv * 16 + l15;                       // this thread's gate unit (lanes 0-15 live)
  const float inv = 1.0f / (127.0f * 127.0f);
  float szp = cm[u] * inv * NLOG2E;
  float srp = cm[u + UNITS] * inv * NLOG2E;
  float scp = cm[u + 2 * UNITS] * inv * N2LOG2E;
  float brcp = bias_r[2 * UNITS + u] * N2LOG2E;

  // hA byte-write base for (row0, u): plane kc=u>>6 (1024 B), lane la=16*((u>>2)&3),
  // byte e=(u&3)+4*((u>>4)&3). Buffer stride 4096 B. Bijective over u (bits 7..0).
  int hwb = (u >> 6) * 1024 + (16 * ((u >> 2) & 3)) * 16 + (u & 3) + 4 * ((u >> 4) & 3);

  float h = 0.0f;
  const unsigned int* mzr = MXzr + (size_t)g * 256 + u;
  const unsigned short* mc = MXc + (size_t)g * 256 + u;
  const size_t mxstride = (size_t)BATCH * 256;
  const float MAGIC = 12582912.0f;             // 2^23 + 2^22

  // prefetch t=0 (lanes>=16 fetch duplicates of the same cache line; harmless)
  unsigned int vzr = *mzr;  mzr += mxstride;
  unsigned int vc  = *mc;   mc  += mxstride;

  __syncthreads();

  for (int t = 0; t < T_STEPS; ++t) {
    // issue NEXT step's mx loads; consumed one full step later -> latency hidden.
    // Final iteration reads one slot past MXzr/MXc (adjacent ws region, unused).
    unsigned int nzr = *mzr;  mzr += mxstride;
    unsigned int nc  = *mc;   mc  += mxstride;

    const i32x4* hp = &hAv[t & 1][0];
    i32x4 af0 = hp[0 * 64 + lane];
    i32x4 af1 = hp[1 * 64 + lane];
    i32x4 af2 = hp[2 * 64 + lane];
    i32x4 af3 = hp[3 * 64 + lane];

    i32x4 az = {0, 0, 0, 0}, ar = {0, 0, 0, 0}, ac = {0, 0, 0, 0};
    az = __builtin_amdgcn_mfma_i32_16x16x64_i8(af0, bz[0], az, 0, 0, 0);
    ar = __builtin_amdgcn_mfma_i32_16x16x64_i8(af0, br[0], ar, 0, 0, 0);
    ac = __builtin_amdgcn_mfma_i32_16x16x64_i8(af0, bc[0], ac, 0, 0, 0);
    az = __builtin_amdgcn_mfma_i32_16x16x64_i8(af1, bz[1], az, 0, 0, 0);
    ar = __builtin_amdgcn_mfma_i32_16x16x64_i8(af1, br[1], ar, 0, 0, 0);
    ac = __builtin_amdgcn_mfma_i32_16x16x64_i8(af1, bc[1], ac, 0, 0, 0);
    az = __builtin_amdgcn_mfma_i32_16x16x64_i8(af2, bz[2], az, 0, 0, 0);
    ar = __builtin_amdgcn_mfma_i32_16x16x64_i8(af2, br[2], ar, 0, 0, 0);
    ac = __builtin_amdgcn_mfma_i32_16x16x64_i8(af2, bc[2], ac, 0, 0, 0);
    az = __builtin_amdgcn_mfma_i32_16x16x64_i8(af3, bz[3], az, 0, 0, 0);
    ar = __builtin_amdgcn_mfma_i32_16x16x64_i8(af3, br[3], ar, 0, 0, 0);
    ac = __builtin_amdgcn_mfma_i32_16x16x64_i8(af3, bc[3], ac, 0, 0, 0);

    // gate phase: lanes 0-15 hold the full (z,r,c) triple for unit u in
    // az[0]/ar[0]/ac[0] (row 0 of the D fragment) — no exchange needed.
    // Lanes >=16 compute junk (zero rows) and never store.
    float zi = (float)az[0];
    float ri = (float)ar[0];
    float ci = (float)ac[0];
    float xz = __uint_as_float(vzr << 16);
    float xr = __uint_as_float(vzr & 0xffff0000u);
    float xc = __uint_as_float(((unsigned int)vc) << 16);
    float tz = 1.0f + EXP2(fminf(__fmaf_rn(zi, szp, xz), 30.0f));
    float tr = 1.0f + EXP2(fminf(__fmaf_rn(ri, srp, xr), 30.0f));
    float R  = __builtin_amdgcn_rcpf(tz * tr);
    float zg = tr * R;                          // sigmoid(z)
    float rg = tz * R;                          // sigmoid(r)
    float mcv = __fmaf_rn(ci, scp, brcp);
    float tc = 1.0f + EXP2(fminf(__fmaf_rn(rg, mcv, xc), 60.0f));
    float cand = __fmaf_rn(2.0f, __builtin_amdgcn_rcpf(tc), -1.0f);  // tanh
    h = __fmaf_rn(zg, h - cand, cand);
    if (lane < 16) {
      float q = __fmaf_rn(h, 127.0f, MAGIC);
      ((signed char*)hAv)[(((t & 1) ^ 1) * 4096) + hwb] = (signed char)(__float_as_uint(q) & 0xFF);
    }
    vzr = nzr;
    vc  = nc;
    // single barrier/step: step t reads hAv[t&1] BEFORE it; step t+1 writes
    // hAv[t&1] AFTER it -> ping-pong is hazard-free with one barrier.
    __syncthreads();
  }

  // epilogue: logits = h @ w_out + b_out -> sigmoid
  if (lane < 16) hout[u] = h;
  __syncthreads();
  if (tid < 64) {
    float p = 0.0f;
#pragma unroll
    for (int k = 0; k < 4; ++k) p += hout[tid + 64 * k] * w_out[tid + 64 * k];
    p += __shfl_down(p, 32, 64);
    p += __shfl_down(p, 16, 64);
    p += __shfl_down(p, 8, 64);
    p += __shfl_down(p, 4, 64);
    p += __shfl_down(p, 2, 64);
    p += __shfl_down(p, 1, 64);
    if (tid == 0) out[g] = sigmoidf_(p + b_out[0]);
  }
}

extern "C" void kernel_launch(void* const* d_in, const int* in_sizes, int n_in,
                              void* d_out, int out_size, void* d_ws, size_t ws_size,
                              hipStream_t stream) {
  const int*   inputs = (const int*)d_in[0];
  const float* emb    = (const float*)d_in[1];
  const float* kern   = (const float*)d_in[2];
  const float* rkern  = (const float*)d_in[3];
  const float* bias_i = (const float*)d_in[4];
  const float* bias_r = (const float*)d_in[5];
  const float* w_out  = (const float*)d_in[6];
  const float* b_out  = (const float*)d_in[7];
  float* out = (float*)d_out;

  char* ws = (char*)d_ws;
  size_t off = 0;
  size_t mxn = (size_t)T_STEPS * BATCH * 256;                          // 6.55M entries
  unsigned int*   MXzr = (unsigned int*)(ws + off);   off += mxn * 4;  // 26.2 MB
  unsigned short* MXc  = (unsigned short*)(ws + off); off += mxn * 2;  // 13.1 MB
  signed char*    w8   = (signed char*)(ws + off);    off += (size_t)W8_BYTES;     // 192 KB
  unsigned short* wfx  = (unsigned short*)(ws + off); off += (size_t)WFX_ELEMS * 2;// 192 KB
  float* cm   = (float*)(ws + off); off += (size_t)N3 * 4;
  float* bsum = (float*)(ws + off); off += (size_t)N3 * 4;
  if (off > ws_size) return;  // insufficient scratch -> visible failure, no corruption

  int prep_blocks = 48 + (WFX_ELEMS + N3 + 255) / 256;
  prep_kernel<<<dim3(prep_blocks), dim3(256), 0, stream>>>(
      kern, rkern, bias_i, bias_r, w8, wfx, bsum, cm);
  mx_kernel<<<dim3(1600), dim3(256), 0, stream>>>(inputs, emb, wfx, bsum, MXzr, MXc);
  gru_kernel<<<dim3(NG), dim3(1024), 0, stream>>>(MXzr, MXc, w8, cm, bias_r, w_out, b_out, out);
}